// Round 8
// baseline (491.149 us; speedup 1.0000x reference)
//
#include <hip/hip_runtime.h>
#include <math.h>

#define NLEV 8
#define D_DIM 1024

struct TB  { float  t[8]; };   // fp32 z-space thresholds (fast path)
struct TBD { double t[8]; };   // fp64 z-space thresholds (repair path)

// ---- DPP rotate-reduce within 16-lane rows (VALU pipe) ----
template<int CTRL>
__device__ __forceinline__ float ror_add(float v) {
    int r = __builtin_amdgcn_update_dpp(0, __float_as_int(v), CTRL, 0xF, 0xF, true);
    return v + __int_as_float(r);
}
__device__ __forceinline__ float red16(float v) {
    v = ror_add<0x121>(v);   // row_ror:1
    v = ror_add<0x122>(v);   // row_ror:2
    v = ror_add<0x124>(v);   // row_ror:4
    v = ror_add<0x128>(v);   // row_ror:8
    return v;                // all 16 lanes of each row hold the row sum
}
__device__ __forceinline__ float wave_allreduce(float v) {
    v = red16(v);
    v += __shfl_xor(v, 16, 64);
    v += __shfl_xor(v, 32, 64);
    return v;
}

// ---------------- single fused kernel: fp32 fast path + inline fp64 repair ----------------
// amdgpu_waves_per_eu(4,4): pins the allocator at the 128-VGPR tier. R7 showed
// __launch_bounds__(256,4) only sets the MINIMUM waves/EU -- the backend still
// chose a 64-VGPR budget (targeting 8 waves/EU that 33KB LDS makes unreachable)
// and spilled ~450MB/dispatch to scratch. min=max=4 removes that incentive.
__global__ __attribute__((amdgpu_flat_work_group_size(256, 256), amdgpu_waves_per_eu(4, 4)))
void fsq_fused(
        const float* __restrict__ xg,
        const float* __restrict__ gg,
        const float* __restrict__ bg,
        const float* __restrict__ Wg,
        float* __restrict__ outg,
        int nrows, TB tb, TBD tbd)
{
    __shared__ float Vs[NLEV][D_DIM];     // 32 KB: V = g*W
    __shared__ float redc1[4][NLEV];
    __shared__ float redc0[4][NLEV];

    const int tid  = (int)threadIdx.x;
    const int lane = tid & 63;
    const int wv   = tid >> 6;

    // ---- stage V into LDS; batched lane-partials for C1=sum(g*W), C0=sum(b*W) ----
    {
        const int col = tid * 4;          // 256 threads x 4 cols = 1024
        const float4 g4 = *(const float4*)(gg + col);
        const float4 b4 = *(const float4*)(bg + col);
        float pc1[NLEV], pc0[NLEV];
        #pragma unroll
        for (int n = 0; n < NLEV; ++n) {
            const float4 w4 = *(const float4*)(Wg + n * D_DIM + col);
            float4 v4;
            v4.x = g4.x * w4.x; v4.y = g4.y * w4.y;
            v4.z = g4.z * w4.z; v4.w = g4.w * w4.w;
            *(float4*)&Vs[n][col] = v4;
            pc1[n] = (v4.x + v4.y) + (v4.z + v4.w);
            pc0[n] = (b4.x * w4.x + b4.y * w4.y) + (b4.z * w4.z + b4.w * w4.w);
        }
        #pragma unroll
        for (int n = 0; n < NLEV; ++n) {
            pc1[n] = wave_allreduce(pc1[n]);
            pc0[n] = wave_allreduce(pc0[n]);
        }
        if (lane == 0) {
            #pragma unroll
            for (int n = 0; n < NLEV; ++n) { redc1[wv][n] = pc1[n]; redc0[wv][n] = pc0[n]; }
        }
    }
    __syncthreads();
    const int nsel = lane & 7;
    const float C1sel = redc1[0][nsel] + redc1[1][nsel] + redc1[2][nsel] + redc1[3][nsel];
    const float C0sel = redc0[0][nsel] + redc0[1][nsel] + redc0[2][nsel] + redc0[3][nsel];

    // ---- row loop: 4 pairs/wave, software-pipelined x prefetch ----
    const long wave_row0 = (long)blockIdx.x * 32 + (long)wv * 8;
    const float4* xb = (const float4*)xg;
    const long base0 = wave_row0 * (D_DIM / 4) + lane;

    float4 xv0[4], xv1[4];
    #pragma unroll
    for (int j = 0; j < 4; ++j) xv0[j] = xb[base0 + j * 64];
    #pragma unroll
    for (int j = 0; j < 4; ++j) xv1[j] = xb[base0 + 256 + j * 64];

    for (int p = 0; p < 4; ++p) {
        const long r0 = wave_row0 + 2 * p;

        // prefetch next pair while computing this one (hides ~900cy HBM latency)
        float4 xn0[4], xn1[4];
        if (p < 3) {
            const long nb = base0 + (long)(p + 1) * 512;
            #pragma unroll
            for (int j = 0; j < 4; ++j) xn0[j] = xb[nb + j * 64];
            #pragma unroll
            for (int j = 0; j < 4; ++j) xn1[j] = xb[nb + 256 + j * 64];
        }

        float s0 = 0.f, s1 = 0.f, sq0 = 0.f, sq1 = 0.f;
        float acc0[NLEV], acc1[NLEV];
        #pragma unroll
        for (int n = 0; n < NLEV; ++n) { acc0[n] = 0.f; acc1[n] = 0.f; }

        #pragma unroll
        for (int j = 0; j < 4; ++j) {
            const int vcol = j * 256 + lane * 4;
            const float4 a = xv0[j];
            const float4 b = xv1[j];
            s0 += (a.x + a.y) + (a.z + a.w);
            s1 += (b.x + b.y) + (b.z + b.w);
            sq0 = fmaf(a.x, a.x, sq0); sq0 = fmaf(a.y, a.y, sq0);
            sq0 = fmaf(a.z, a.z, sq0); sq0 = fmaf(a.w, a.w, sq0);
            sq1 = fmaf(b.x, b.x, sq1); sq1 = fmaf(b.y, b.y, sq1);
            sq1 = fmaf(b.z, b.z, sq1); sq1 = fmaf(b.w, b.w, sq1);
            #pragma unroll
            for (int n = 0; n < NLEV; ++n) {
                const float4 v4 = *(const float4*)&Vs[n][vcol];  // ds_read_b128, reused 8x
                acc0[n] = fmaf(a.x, v4.x, acc0[n]);
                acc0[n] = fmaf(a.y, v4.y, acc0[n]);
                acc0[n] = fmaf(a.z, v4.z, acc0[n]);
                acc0[n] = fmaf(a.w, v4.w, acc0[n]);
                acc1[n] = fmaf(b.x, v4.x, acc1[n]);
                acc1[n] = fmaf(b.y, v4.y, acc1[n]);
                acc1[n] = fmaf(b.z, v4.z, acc1[n]);
                acc1[n] = fmaf(b.w, v4.w, acc1[n]);
            }
        }

        s0 = red16(s0); s1 = red16(s1); sq0 = red16(sq0); sq1 = red16(sq1);
        #pragma unroll
        for (int n = 0; n < NLEV; ++n) { acc0[n] = red16(acc0[n]); acc1[n] = red16(acc1[n]); }

        float u0, u1, u2, u3, w0, w1;
        u0 = (lane & 4) ? acc0[4] : acc0[0];
        u1 = (lane & 4) ? acc0[5] : acc0[1];
        u2 = (lane & 4) ? acc0[6] : acc0[2];
        u3 = (lane & 4) ? acc0[7] : acc0[3];
        w0 = (lane & 2) ? u2 : u0;
        w1 = (lane & 2) ? u3 : u1;
        float S0 = (lane & 1) ? w1 : w0;
        u0 = (lane & 4) ? acc1[4] : acc1[0];
        u1 = (lane & 4) ? acc1[5] : acc1[1];
        u2 = (lane & 4) ? acc1[6] : acc1[2];
        u3 = (lane & 4) ? acc1[7] : acc1[3];
        w0 = (lane & 2) ? u2 : u0;
        w1 = (lane & 2) ? u3 : u1;
        float S1 = (lane & 1) ? w1 : w0;

        S0  += __shfl_xor(S0, 16, 64);  S0  += __shfl_xor(S0, 32, 64);
        S1  += __shfl_xor(S1, 16, 64);  S1  += __shfl_xor(S1, 32, 64);
        s0  += __shfl_xor(s0, 16, 64);  s0  += __shfl_xor(s0, 32, 64);
        s1  += __shfl_xor(s1, 16, 64);  s1  += __shfl_xor(s1, 32, 64);
        sq0 += __shfl_xor(sq0, 16, 64); sq0 += __shfl_xor(sq0, 32, 64);
        sq1 += __shfl_xor(sq1, 16, 64); sq1 += __shfl_xor(sq1, 32, 64);

        bool flag = false;
        if (lane < 16) {
            const float S  = (lane < 8) ? S0  : S1;
            const float ss = (lane < 8) ? s0  : s1;
            const float qq = (lane < 8) ? sq0 : sq1;
            const long row = (lane < 8) ? r0 : (r0 + 1);
            const float mean = ss * (1.0f / 1024.0f);
            const float var  = qq * (1.0f / 1024.0f) - mean * mean;
            const float rstd = 1.0f / sqrtf(var + 1e-5f);
            const float z = rstd * (S - mean * C1sel) + C0sel;
            int cnt = 0;
            float mind = 1e30f;
            #pragma unroll
            for (int k = 0; k < 8; ++k) {
                cnt += (z > tb.t[k]) ? 1 : 0;
                mind = fminf(mind, fabsf(z - tb.t[k]));
            }
            outg[row * NLEV + nsel] = (float)(cnt - 4);
            flag = (mind < 1.0e-3f);
        }
        const unsigned long long bal = __ballot(flag);

        // ---- inline fp64 repair (cold, wave-uniform branch; ~8% of pairs) ----
        if (bal != 0ULL) {
            #pragma unroll 1
            for (int half = 0; half < 2; ++half) {
                if (!(bal & (half ? 0xFF00ull : 0x00FFull))) continue;
                const long row = r0 + half;
                const float4* xb4 = (const float4*)(xg + row * D_DIM);

                float4 xr[4];
                #pragma unroll
                for (int j = 0; j < 4; ++j) xr[j] = xb4[j * 64 + lane];  // L2-hot

                double s = 0.0, sq = 0.0;
                #pragma unroll
                for (int j = 0; j < 4; ++j) {
                    const double x0 = (double)xr[j].x, x1 = (double)xr[j].y;
                    const double x2 = (double)xr[j].z, x3 = (double)xr[j].w;
                    s += ((x0 + x1) + (x2 + x3));
                    sq = fma(x0, x0, sq); sq = fma(x1, x1, sq);
                    sq = fma(x2, x2, sq); sq = fma(x3, x3, sq);
                }
                #pragma unroll
                for (int off = 32; off >= 1; off >>= 1) {
                    s  += __shfl_xor(s, off, 64);
                    sq += __shfl_xor(sq, off, 64);
                }
                const double mean = s * (1.0 / 1024.0);
                const double var  = sq * (1.0 / 1024.0) - mean * mean;
                const double rstd = 1.0 / sqrt(var + 1e-5);

                double acc[NLEV];
                #pragma unroll
                for (int n = 0; n < NLEV; ++n) acc[n] = 0.0;
                #pragma unroll
                for (int j = 0; j < 4; ++j) {
                    const int col = j * 256 + lane * 4;
                    const float4 g4 = *(const float4*)(gg + col);
                    const float4 b4 = *(const float4*)(bg + col);
                    const double y0 = fma(((double)xr[j].x - mean) * rstd, (double)g4.x, (double)b4.x);
                    const double y1 = fma(((double)xr[j].y - mean) * rstd, (double)g4.y, (double)b4.y);
                    const double y2 = fma(((double)xr[j].z - mean) * rstd, (double)g4.z, (double)b4.z);
                    const double y3 = fma(((double)xr[j].w - mean) * rstd, (double)g4.w, (double)b4.w);
                    #pragma unroll
                    for (int n = 0; n < NLEV; ++n) {
                        const float4 w4 = *(const float4*)(Wg + n * D_DIM + col);
                        acc[n] = fma(y0, (double)w4.x, acc[n]);
                        acc[n] = fma(y1, (double)w4.y, acc[n]);
                        acc[n] = fma(y2, (double)w4.z, acc[n]);
                        acc[n] = fma(y3, (double)w4.w, acc[n]);
                    }
                }
                #pragma unroll
                for (int off = 32; off >= 1; off >>= 1) {
                    #pragma unroll
                    for (int n = 0; n < NLEV; ++n) acc[n] += __shfl_xor(acc[n], off, 64);
                }
                if (lane < NLEV) {
                    double a0 = (lane & 4) ? acc[4] : acc[0];
                    double a1 = (lane & 4) ? acc[5] : acc[1];
                    double a2 = (lane & 4) ? acc[6] : acc[2];
                    double a3 = (lane & 4) ? acc[7] : acc[3];
                    double b0 = (lane & 2) ? a2 : a0;
                    double b1 = (lane & 2) ? a3 : a1;
                    const double z = (lane & 1) ? b1 : b0;
                    int c = 0;
                    #pragma unroll
                    for (int k = 0; k < 8; ++k) c += (z > tbd.t[k]) ? 1 : 0;
                    outg[row * NLEV + lane] = (float)(c - 4);
                }
            }
        }

        // rotate pipeline
        if (p < 3) {
            #pragma unroll
            for (int j = 0; j < 4; ++j) { xv0[j] = xn0[j]; xv1[j] = xn1[j]; }
        }
    }
}

extern "C" void kernel_launch(void* const* d_in, const int* in_sizes, int n_in,
                              void* d_out, int out_size, void* d_ws, size_t ws_size,
                              hipStream_t stream) {
    (void)n_in; (void)out_size; (void)d_ws; (void)ws_size;
    const float* regrs = (const float*)d_in[0];
    const float* ln_w  = (const float*)d_in[1];
    const float* ln_b  = (const float*)d_in[2];
    const float* W     = (const float*)d_in[3];
    float* out = (float*)d_out;

    const int nrows = in_sizes[0] / D_DIM;  // 32768
    const int nblocks = (nrows + 31) / 32;  // 32 rows/block -> 1024 blocks

    TB tb; TBD tbd;
    for (int k = 0; k < 8; ++k) {
        const double y = ((double)k - 3.5) / 3.996;
        tbd.t[k] = atanh(y);           // fp64 z-space rounding boundaries
        tb.t[k]  = (float)tbd.t[k];
    }

    fsq_fused<<<nblocks, 256, 0, stream>>>(regrs, ln_w, ln_b, W, out, nrows, tb, tbd);
}

// Round 9
// 218.650 us; speedup vs baseline: 2.2463x; 2.2463x over previous
//
#include <hip/hip_runtime.h>
#include <math.h>

#define NLEV 8
#define D_DIM 1024

struct TB  { float  t[8]; };   // fp32 z-space thresholds (fast path)
struct TBD { double t[8]; };   // fp64 z-space thresholds (repair path)

// ---- DPP rotate-reduce within 16-lane rows (VALU pipe) ----
template<int CTRL>
__device__ __forceinline__ float ror_add(float v) {
    int r = __builtin_amdgcn_update_dpp(0, __float_as_int(v), CTRL, 0xF, 0xF, true);
    return v + __int_as_float(r);
}
__device__ __forceinline__ float red16(float v) {
    v = ror_add<0x121>(v);   // row_ror:1
    v = ror_add<0x122>(v);   // row_ror:2
    v = ror_add<0x124>(v);   // row_ror:4
    v = ror_add<0x128>(v);   // row_ror:8
    return v;                // all 16 lanes of each row hold the row sum
}
__device__ __forceinline__ float wave_allreduce(float v) {
    v = red16(v);
    v += __shfl_xor(v, 16, 64);
    v += __shfl_xor(v, 32, 64);
    return v;
}

// ---------------- phase 1: fp32 fast path, ONE row per wave-iteration ----------------
// Designed to live within a 64-VGPR budget (R7/R8 proved the backend pins 64
// regardless of launch_bounds/waves_per_eu attrs and spills the excess):
// x 16 + acc 10 + C/addr/misc ~20 => ~45 live, zero spill by construction.
// Latency hiding comes from TLP (16 waves/CU), not prefetch arrays.
__global__ __launch_bounds__(256) void fsq_main(
        const float* __restrict__ xg,
        const float* __restrict__ gg,
        const float* __restrict__ bg,
        const float* __restrict__ Wg,
        float* __restrict__ outg,
        unsigned int* __restrict__ wl,  // wl[0]=cnt, wl[16..]=rows
        int wl_cap, int nrows, TB tb)
{
    __shared__ float Vs[NLEV][D_DIM];     // 32 KB: V = g*W
    __shared__ float redc1[4][NLEV];
    __shared__ float redc0[4][NLEV];

    const int tid  = (int)threadIdx.x;
    const int lane = tid & 63;
    const int wv   = tid >> 6;

    // ---- stage V into LDS; block-reduce C1=sum(g*W), C0=sum(b*W) ----
    {
        const int col = tid * 4;          // 256 threads x 4 cols = 1024
        const float4 g4 = *(const float4*)(gg + col);
        const float4 b4 = *(const float4*)(bg + col);
        float pc1[NLEV], pc0[NLEV];
        #pragma unroll
        for (int n = 0; n < NLEV; ++n) {
            const float4 w4 = *(const float4*)(Wg + n * D_DIM + col);
            float4 v4;
            v4.x = g4.x * w4.x; v4.y = g4.y * w4.y;
            v4.z = g4.z * w4.z; v4.w = g4.w * w4.w;
            *(float4*)&Vs[n][col] = v4;
            pc1[n] = (v4.x + v4.y) + (v4.z + v4.w);
            pc0[n] = (b4.x * w4.x + b4.y * w4.y) + (b4.z * w4.z + b4.w * w4.w);
        }
        #pragma unroll
        for (int n = 0; n < NLEV; ++n) {
            pc1[n] = wave_allreduce(pc1[n]);
            pc0[n] = wave_allreduce(pc0[n]);
        }
        if (lane == 0) {
            #pragma unroll
            for (int n = 0; n < NLEV; ++n) { redc1[wv][n] = pc1[n]; redc0[wv][n] = pc0[n]; }
        }
    }
    __syncthreads();
    const int nsel = lane & 7;
    const float C1sel = redc1[0][nsel] + redc1[1][nsel] + redc1[2][nsel] + redc1[3][nsel];
    const float C0sel = redc0[0][nsel] + redc0[1][nsel] + redc0[2][nsel] + redc0[3][nsel];

    // ---- row loop: 8 rows per wave, one at a time ----
    const long wave_row0 = (long)blockIdx.x * 32 + (long)wv * 8;
    const float4* xb = (const float4*)xg;

    for (int p = 0; p < 8; ++p) {
        const long row = wave_row0 + p;
        if (row >= nrows) break;

        const float4* xr = xb + row * (D_DIM / 4);
        float4 xv0 = xr[lane];
        float4 xv1 = xr[64 + lane];
        float4 xv2 = xr[128 + lane];
        float4 xv3 = xr[192 + lane];

        float s = 0.f, sq = 0.f;
        float acc[NLEV];
        #pragma unroll
        for (int n = 0; n < NLEV; ++n) acc[n] = 0.f;

        #pragma unroll
        for (int j = 0; j < 4; ++j) {
            const float4 a = (j == 0) ? xv0 : (j == 1) ? xv1 : (j == 2) ? xv2 : xv3;
            const int vcol = j * 256 + lane * 4;
            s += (a.x + a.y) + (a.z + a.w);
            sq = fmaf(a.x, a.x, sq); sq = fmaf(a.y, a.y, sq);
            sq = fmaf(a.z, a.z, sq); sq = fmaf(a.w, a.w, sq);
            #pragma unroll
            for (int n = 0; n < NLEV; ++n) {
                const float4 v4 = *(const float4*)&Vs[n][vcol];  // ds_read_b128
                acc[n] = fmaf(a.x, v4.x, acc[n]);
                acc[n] = fmaf(a.y, v4.y, acc[n]);
                acc[n] = fmaf(a.z, v4.z, acc[n]);
                acc[n] = fmaf(a.w, v4.w, acc[n]);
            }
        }

        // within-16 DPP reduce, select n=(lane&7), finish with 2 shuffles
        s = red16(s); sq = red16(sq);
        #pragma unroll
        for (int n = 0; n < NLEV; ++n) acc[n] = red16(acc[n]);

        float u0 = (lane & 4) ? acc[4] : acc[0];
        float u1 = (lane & 4) ? acc[5] : acc[1];
        float u2 = (lane & 4) ? acc[6] : acc[2];
        float u3 = (lane & 4) ? acc[7] : acc[3];
        float w0 = (lane & 2) ? u2 : u0;
        float w1 = (lane & 2) ? u3 : u1;
        float Ssel = (lane & 1) ? w1 : w0;

        Ssel += __shfl_xor(Ssel, 16, 64); Ssel += __shfl_xor(Ssel, 32, 64);
        s    += __shfl_xor(s, 16, 64);    s    += __shfl_xor(s, 32, 64);
        sq   += __shfl_xor(sq, 16, 64);   sq   += __shfl_xor(sq, 32, 64);

        bool flag = false;
        if (lane < NLEV) {
            const float mean = s * (1.0f / 1024.0f);
            const float var  = sq * (1.0f / 1024.0f) - mean * mean;
            const float rstd = 1.0f / sqrtf(var + 1e-5f);
            const float z = rstd * (Ssel - mean * C1sel) + C0sel;
            int cnt = 0;
            float mind = 1e30f;
            #pragma unroll
            for (int k = 0; k < 8; ++k) {
                cnt += (z > tb.t[k]) ? 1 : 0;
                mind = fminf(mind, fabsf(z - tb.t[k]));
            }
            outg[row * NLEV + lane] = (float)(cnt - 4);
            flag = (mind < 1.0e-3f);   // fp32 z error ~1e-4 worst case
        }
        const unsigned long long bal = __ballot(flag);
        if (lane == 0 && bal != 0ULL) {
            const unsigned i = atomicAdd(wl, 1u);
            if (i < (unsigned)wl_cap) wl[16 + i] = (unsigned)row;
        }
    }
}

// ---------------- phase 2: fp64 repair, wave-per-row ----------------
// Early-exit before any work. Pass 2 RELOADS x from L2 instead of keeping it
// resident, capping peak live regs at ~50 (fits the 64-VGPR budget, no spill).
__global__ __launch_bounds__(256) void fsq_fix(
        const float* __restrict__ xg,
        const float* __restrict__ gg,
        const float* __restrict__ bg,
        const float* __restrict__ Wg,
        float* __restrict__ outg,
        const unsigned int* __restrict__ wl,
        int wl_cap, TBD tbd)
{
    const int tid  = (int)threadIdx.x;
    const int lane = tid & 63;
    const int wv   = tid >> 6;
    const unsigned wave   = blockIdx.x * 4 + wv;
    const unsigned nwaves = gridDim.x * 4;

    unsigned cnt = wl[0];
    if (cnt > (unsigned)wl_cap) cnt = (unsigned)wl_cap;
    if (wave >= cnt) return;            // idle waves do ZERO work

    for (unsigned it = wave; it < cnt; it += nwaves) {
        const long row = (long)wl[16 + it];
        const float4* xb4 = (const float4*)(xg + row * D_DIM);

        // pass 1: mean / rstd in fp64 (x consumed immediately, not kept)
        double s = 0.0, sq = 0.0;
        #pragma unroll
        for (int j = 0; j < 4; ++j) {
            const float4 x4 = xb4[j * 64 + lane];
            const double x0 = (double)x4.x, x1 = (double)x4.y;
            const double x2 = (double)x4.z, x3 = (double)x4.w;
            s += ((x0 + x1) + (x2 + x3));
            sq = fma(x0, x0, sq); sq = fma(x1, x1, sq);
            sq = fma(x2, x2, sq); sq = fma(x3, x3, sq);
        }
        #pragma unroll
        for (int off = 32; off >= 1; off >>= 1) {
            s  += __shfl_xor(s, off, 64);
            sq += __shfl_xor(sq, off, 64);
        }
        const double mean = s * (1.0 / 1024.0);
        const double var  = sq * (1.0 / 1024.0) - mean * mean;
        const double rstd = 1.0 / sqrt(var + 1e-5);

        // pass 2: z_n = sum(y_i * W_ni), y = (x-mean)*rstd*g + b; x reloaded (L2-hot)
        double acc[NLEV];
        #pragma unroll
        for (int n = 0; n < NLEV; ++n) acc[n] = 0.0;
        #pragma unroll
        for (int j = 0; j < 4; ++j) {
            const int col = j * 256 + lane * 4;
            const float4 x4 = xb4[j * 64 + lane];
            const float4 g4 = *(const float4*)(gg + col);
            const float4 b4 = *(const float4*)(bg + col);
            const double y0 = fma(((double)x4.x - mean) * rstd, (double)g4.x, (double)b4.x);
            const double y1 = fma(((double)x4.y - mean) * rstd, (double)g4.y, (double)b4.y);
            const double y2 = fma(((double)x4.z - mean) * rstd, (double)g4.z, (double)b4.z);
            const double y3 = fma(((double)x4.w - mean) * rstd, (double)g4.w, (double)b4.w);
            #pragma unroll
            for (int n = 0; n < NLEV; ++n) {
                const float4 w4 = *(const float4*)(Wg + n * D_DIM + col);
                acc[n] = fma(y0, (double)w4.x, acc[n]);
                acc[n] = fma(y1, (double)w4.y, acc[n]);
                acc[n] = fma(y2, (double)w4.z, acc[n]);
                acc[n] = fma(y3, (double)w4.w, acc[n]);
            }
        }
        #pragma unroll
        for (int off = 32; off >= 1; off >>= 1) {
            #pragma unroll
            for (int n = 0; n < NLEV; ++n) acc[n] += __shfl_xor(acc[n], off, 64);
        }

        if (lane < NLEV) {
            double a0 = (lane & 4) ? acc[4] : acc[0];
            double a1 = (lane & 4) ? acc[5] : acc[1];
            double a2 = (lane & 4) ? acc[6] : acc[2];
            double a3 = (lane & 4) ? acc[7] : acc[3];
            double b0 = (lane & 2) ? a2 : a0;
            double b1 = (lane & 2) ? a3 : a1;
            const double z = (lane & 1) ? b1 : b0;
            int c = 0;
            #pragma unroll
            for (int k = 0; k < 8; ++k) c += (z > tbd.t[k]) ? 1 : 0;
            outg[row * NLEV + lane] = (float)(c - 4);
        }
    }
}

extern "C" void kernel_launch(void* const* d_in, const int* in_sizes, int n_in,
                              void* d_out, int out_size, void* d_ws, size_t ws_size,
                              hipStream_t stream) {
    (void)n_in; (void)out_size;
    const float* regrs = (const float*)d_in[0];
    const float* ln_w  = (const float*)d_in[1];
    const float* ln_b  = (const float*)d_in[2];
    const float* W     = (const float*)d_in[3];
    float* out = (float*)d_out;

    const int nrows = in_sizes[0] / D_DIM;  // 32768
    const int nblocks = (nrows + 31) / 32;  // 32 rows/block -> 1024 blocks

    unsigned int* wl = (unsigned int*)d_ws;
    long cap_l = ((long)(ws_size / 4)) - 16;
    if (cap_l < 0) cap_l = 0;
    if (cap_l > nrows) cap_l = nrows;
    const int wl_cap = (int)cap_l;

    TB tb; TBD tbd;
    for (int k = 0; k < 8; ++k) {
        const double y = ((double)k - 3.5) / 3.996;
        tbd.t[k] = atanh(y);           // fp64 z-space rounding boundaries
        tb.t[k]  = (float)tbd.t[k];
    }

    hipMemsetAsync(d_ws, 0, 64, stream);  // zero worklist counter
    fsq_main<<<nblocks, 256, 0, stream>>>(regrs, ln_w, ln_b, W, out, wl, wl_cap, nrows, tb);
    fsq_fix<<<128, 256, 0, stream>>>(regrs, ln_w, ln_b, W, out, wl, wl_cap, tbd);
}